// Round 1
// baseline (830.295 us; speedup 1.0000x reference)
//
#include <hip/hip_runtime.h>
#include <math.h>

// SSVI: out = y*0.5*(1 + rho*pl + sqrt(pl^2 + 2 rho pl + 1)), pl = phi*logm,
// phi = eta / (y^gamma * (1+y)^(1-gamma)).
// Outputs (concat flat): [out, zeros, d out/d logm, d2 out/d logm^2], each N floats.
//
// Closed-form derivatives:
//   s   = sqrt(pl^2 + 2 rho pl + 1)
//   g1  = 0.5*y*phi*(rho + (pl+rho)/s)
//   g2  = 0.5*y*phi^2*(1 - rho^2)/s^3     [since s^2-(pl+rho)^2 = 1-rho^2]

__global__ __launch_bounds__(256) void ssvi_kernel(
    const float4* __restrict__ logm4,
    const float4* __restrict__ y4,
    const float* __restrict__ raw_rho,
    const float* __restrict__ raw_eta,
    const float* __restrict__ raw_gamma,
    float4* __restrict__ out4,   // 4*n4 float4s
    int n4)
{
    int i = blockIdx.x * blockDim.x + threadIdx.x;
    if (i >= n4) return;

    // Scalar params: broadcast loads, hit L1/L2 after first wave. Cheap.
    const float rho   = tanhf(raw_rho[0]);
    const float eta   = expf(raw_eta[0]);
    const float gamma = expf(raw_gamma[0]);
    const float one_m_rho2 = 1.0f - rho * rho;

    float4 lm = logm4[i];
    float4 yv = y4[i];

    float4 o, g1, g2;
    const float* lmp = &lm.x;
    const float* yp  = &yv.x;
    float* op  = &o.x;
    float* g1p = &g1.x;
    float* g2p = &g2.x;

    #pragma unroll
    for (int k = 0; k < 4; ++k) {
        float y  = yp[k];
        float l  = lmp[k];
        // phi = eta / (y^gamma * (1+y)^(1-gamma))
        float phi = eta / (powf(y, gamma) * powf(1.0f + y, 1.0f - gamma));
        float pl  = phi * l;
        float s2  = pl * pl + 2.0f * rho * pl + 1.0f;
        float s   = sqrtf(s2);
        float inv_s = 1.0f / s;
        float half_y = 0.5f * y;
        op[k]  = half_y * (1.0f + rho * pl + s);
        g1p[k] = half_y * phi * (rho + (pl + rho) * inv_s);
        g2p[k] = half_y * phi * phi * one_m_rho2 * (inv_s * inv_s * inv_s);
    }

    out4[i] = o;
    out4[(size_t)n4 + i] = make_float4(0.0f, 0.0f, 0.0f, 0.0f);  // grad_ttm1
    out4[2 * (size_t)n4 + i] = g1;
    out4[3 * (size_t)n4 + i] = g2;
}

extern "C" void kernel_launch(void* const* d_in, const int* in_sizes, int n_in,
                              void* d_out, int out_size, void* d_ws, size_t ws_size,
                              hipStream_t stream) {
    const float4* logm4 = (const float4*)d_in[0];
    const float4* y4    = (const float4*)d_in[1];
    const float* raw_rho   = (const float*)d_in[2];
    const float* raw_eta   = (const float*)d_in[3];
    const float* raw_gamma = (const float*)d_in[4];
    float4* out4 = (float4*)d_out;

    int n  = in_sizes[0];        // 33554432, divisible by 4
    int n4 = n / 4;
    int block = 256;
    int grid = (n4 + block - 1) / block;
    ssvi_kernel<<<grid, block, 0, stream>>>(logm4, y4, raw_rho, raw_eta, raw_gamma,
                                            out4, n4);
}